// Round 6
// baseline (215.644 us; speedup 1.0000x reference)
//
#include <hip/hip_runtime.h>
#include <math.h>

#define NN 2048
#define BB 4
#define HD 128
#define CNUM 8
#define WPB 4               // waves (= centers) per block in k_dist
#define PCHUNK 64           // nodes per block in k_pool1
#define NCHUNKS (NN / PCHUNK)

__device__ __forceinline__ void top3_insert(float sq, int j,
        float& s0, float& s1, float& s2, int& i0, int& i1, int& i2) {
    if (sq < s2) {                        // strict <: lower j wins ties (j increasing)
        if (sq < s1) {
            s2 = s1; i2 = i1;
            if (sq < s0) { s1 = s0; i1 = i0; s0 = sq; i0 = j; }
            else         { s1 = sq; i1 = j; }
        } else { s2 = sq; i2 = j; }
    }
}

// merge-insert with explicit (sq, j) lexicographic tie-break
__device__ __forceinline__ void top3_insert_lex(float sq, int j,
        float& s0, float& s1, float& s2, int& i0, int& i1, int& i2) {
    if (sq < s2 || (sq == s2 && j < i2)) {
        if (sq < s1 || (sq == s1 && j < i1)) {
            s2 = s1; i2 = i1;
            if (sq < s0 || (sq == s0 && j < i0)) { s1 = s0; i1 = i0; s0 = sq; i0 = j; }
            else                                 { s1 = sq; i1 = j; }
        } else { s2 = sq; i2 = j; }
    }
}

// K0: pack (x,y,z,|p|^2) once to global. Removes the per-block staging
// prologue that dominated wave lifetime in R1-R5 (VALUBusy pinned at 17%).
__global__ void k_prep(const float* __restrict__ x, float4* __restrict__ pts) {
    const int t = blockIdx.x * 256 + threadIdx.x;   // [0, B*NN)
    const float a = x[3 * t], c = x[3 * t + 1], d = x[3 * t + 2];
    pts[t] = make_float4(a, c, d, a * a + c * c + d * d);
}

// K1: one wave per center. No LDS, no barrier: lanes scan pts[] directly with
// coalesced dwordx4 loads (L2-resident, 32 KB/batch), 4 independent loads in
// flight per iteration. Butterfly merge, fused exp/de/dv epilogue.
__global__ __launch_bounds__(256) void k_dist(
        const float4* __restrict__ pts,
        int* __restrict__ idx, float* __restrict__ vals,
        float* __restrict__ de, float* __restrict__ dv) {
    const int b = blockIdx.y;
    const float4* pb = pts + b * NN;
    const int wave = threadIdx.x >> 6;
    const int lane = threadIdx.x & 63;
    const int i = blockIdx.x * WPB + wave;          // this wave's center
    const float4 ci = pb[i];                        // wave-uniform -> broadcast
    float s0 = INFINITY, s1 = INFINITY, s2 = INFINITY;
    int i0 = -1, i1 = -1, i2 = -1;
    float dsA = 0.f, dsB = 0.f;
    for (int t = lane; t < NN; t += 256) {          // 8 iterations, 4 elems each
        const float4 pa = pb[t];
        const float4 pbv = pb[t + 64];
        const float4 pc = pb[t + 128];
        const float4 pd = pb[t + 192];
        const float qa = fmaxf(ci.w + pa.w  - 2.0f * (ci.x * pa.x  + ci.y * pa.y  + ci.z * pa.z ), 0.0f);
        const float qb = fmaxf(ci.w + pbv.w - 2.0f * (ci.x * pbv.x + ci.y * pbv.y + ci.z * pbv.z), 0.0f);
        const float qc = fmaxf(ci.w + pc.w  - 2.0f * (ci.x * pc.x  + ci.y * pc.y  + ci.z * pc.z ), 0.0f);
        const float qd = fmaxf(ci.w + pd.w  - 2.0f * (ci.x * pd.x  + ci.y * pd.y  + ci.z * pd.z ), 0.0f);
        dsA += sqrtf(qa + 1e-12f) + sqrtf(qc + 1e-12f);
        dsB += sqrtf(qb + 1e-12f) + sqrtf(qd + 1e-12f);
        top3_insert(qa, t,       s0, s1, s2, i0, i1, i2);
        top3_insert(qb, t + 64,  s0, s1, s2, i0, i1, i2);
        top3_insert(qc, t + 128, s0, s1, s2, i0, i1, i2);
        top3_insert(qd, t + 192, s0, s1, s2, i0, i1, i2);
    }
    float dsum = dsA + dsB;
    // butterfly merge across the wave (all lanes converge to same result)
    for (int off = 32; off > 0; off >>= 1) {
        float o0 = __shfl_xor(s0, off), o1 = __shfl_xor(s1, off), o2 = __shfl_xor(s2, off);
        int   j0 = __shfl_xor(i0, off), j1 = __shfl_xor(i1, off), j2 = __shfl_xor(i2, off);
        dsum += __shfl_xor(dsum, off);
        top3_insert_lex(o0, j0, s0, s1, s2, i0, i1, i2);
        top3_insert_lex(o1, j1, s0, s1, s2, i0, i1, i2);
        top3_insert_lex(o2, j2, s0, s1, s2, i0, i1, i2);
    }
    if (lane == 0) {
        const float avg = dsum * (1.0f / NN);
        const float inva2 = 1.0f / (avg * avg);
        const float v0 = expf(-s0 * inva2);
        const float v1 = expf(-s1 * inva2);
        const float v2 = expf(-s2 * inva2);
        const int base = (b * NN + i) * 3;
        idx[base] = i0; idx[base + 1] = i1; idx[base + 2] = i2;
        vals[base] = v0; vals[base + 1] = v1; vals[base + 2] = v2;
        de[b * NN + i] = v0 + v1 + v2;
        atomicAdd(&dv[b * NN + i0], v0);
        atomicAdd(&dv[b * NN + i1], v1);
        atomicAdd(&dv[b * NN + i2], v2);
    }
}

// K2: first G-application on W1. 256-thread blocks, 2 edges per block.
__global__ void k_conv1(const float* __restrict__ W1, const int* __restrict__ idx,
                        const float* __restrict__ vals, const float* __restrict__ de,
                        const float* __restrict__ dv, float* __restrict__ Z1) {
    const int e = blockIdx.x * 2 + (threadIdx.x >> 7);
    const int b = blockIdx.y, h = threadIdx.x & (HD - 1);
    const int base = (b * NN + e) * 3;
    const int j0 = idx[base], j1 = idx[base + 1], j2 = idx[base + 2];
    const float v0 = vals[base], v1 = vals[base + 1], v2 = vals[base + 2];
    const float ide = 1.0f / de[b * NN + e];
    const float g0 = v0 * rsqrtf(dv[b * NN + j0]);
    const float g1 = v1 * rsqrtf(dv[b * NN + j1]);
    const float g2 = v2 * rsqrtf(dv[b * NN + j2]);
    const float y = ide * (g0 * W1[j0 * HD + h] + g1 * W1[j1 * HD + h] + g2 * W1[j2 * HD + h]);
    atomicAdd(&Z1[((size_t)(b * NN + j0)) * HD + h], v0 * y);
    atomicAdd(&Z1[((size_t)(b * NN + j1)) * HD + h], v1 * y);
    atomicAdd(&Z1[((size_t)(b * NN + j2)) * HD + h], v2 * y);
}

// K3: second G-application on f1 = dv2*Z1 + b1.
__global__ void k_conv2(const float* __restrict__ b1, const int* __restrict__ idx,
                        const float* __restrict__ vals, const float* __restrict__ de,
                        const float* __restrict__ dv, const float* __restrict__ Z1,
                        float* __restrict__ Z2) {
    const int e = blockIdx.x * 2 + (threadIdx.x >> 7);
    const int b = blockIdx.y, h = threadIdx.x & (HD - 1);
    const int base = (b * NN + e) * 3;
    const int j0 = idx[base], j1 = idx[base + 1], j2 = idx[base + 2];
    const float v0 = vals[base], v1 = vals[base + 1], v2 = vals[base + 2];
    const float ide = 1.0f / de[b * NN + e];
    const float bh = b1[h];
    const float d0 = rsqrtf(dv[b * NN + j0]);
    const float d1 = rsqrtf(dv[b * NN + j1]);
    const float d2 = rsqrtf(dv[b * NN + j2]);
    const float f0 = d0 * Z1[((size_t)(b * NN + j0)) * HD + h] + bh;
    const float f1 = d1 * Z1[((size_t)(b * NN + j1)) * HD + h] + bh;
    const float f2 = d2 * Z1[((size_t)(b * NN + j2)) * HD + h] + bh;
    const float y = ide * (v0 * d0 * f0 + v1 * d1 * f1 + v2 * d2 * f2);
    atomicAdd(&Z2[((size_t)(b * NN + j0)) * HD + h], v0 * y);
    atomicAdd(&Z2[((size_t)(b * NN + j1)) * HD + h], v1 * y);
    atomicAdd(&Z2[((size_t)(b * NN + j2)) * HD + h], v2 * y);
}

// K4a: partial max over 64-node chunks. grid (B, 32) x 128 threads.
__global__ void k_pool1(const float* __restrict__ dv, const float* __restrict__ Z2,
                        float* __restrict__ pmax) {
    const int b = blockIdx.x, ch = blockIdx.y, h = threadIdx.x;
    const int v0 = ch * PCHUNK;
    float mx = -INFINITY;
    for (int v = v0; v < v0 + PCHUNK; ++v) {
        const float d2 = rsqrtf(dv[b * NN + v]);
        mx = fmaxf(mx, d2 * Z2[((size_t)(b * NN + v)) * HD + h]);
    }
    pmax[(b * NCHUNKS + ch) * HD + h] = mx;
}

// K4b: merge partial maxes + classifier. grid B x 128 threads.
__global__ void k_pool2(const float* __restrict__ Wc, const float* __restrict__ bc,
                        const float* __restrict__ pmax, float* __restrict__ out) {
    __shared__ float smax[HD];
    const int b = blockIdx.x, h = threadIdx.x;
    float mx = -INFINITY;
    for (int c = 0; c < NCHUNKS; ++c)
        mx = fmaxf(mx, pmax[(b * NCHUNKS + c) * HD + h]);
    smax[h] = mx;
    __syncthreads();
    if (h < CNUM) {
        float acc = bc[h];
        for (int q = 0; q < HD; ++q) acc += smax[q] * Wc[q * CNUM + h];
        out[b * CNUM + h] = acc;
    }
}

extern "C" void kernel_launch(void* const* d_in, const int* in_sizes, int n_in,
                              void* d_out, int out_size, void* d_ws, size_t ws_size,
                              hipStream_t stream) {
    const float* x  = (const float*)d_in[0];   // [B,N,3]
    const float* W1 = (const float*)d_in[1];   // [N,H1]
    const float* b1 = (const float*)d_in[2];   // [H1]
    const float* Wc = (const float*)d_in[3];   // [H1,C]
    const float* bc = (const float*)d_in[4];   // [C]
    float* out = (float*)d_out;                // [B,C]

    float* ws = (float*)d_ws;
    float* dv   = ws;                                  // B*N           (zeroed)
    float* Z1   = dv + BB * NN;                        // B*N*HD        (zeroed)
    float* Z2   = Z1 + (size_t)BB * NN * HD;           // B*N*HD        (zeroed)
    float* vals = Z2 + (size_t)BB * NN * HD;           // B*N*3
    float* de   = vals + BB * NN * 3;                  // B*N
    int*   idx  = (int*)(de + BB * NN);                // B*N*3
    float* pmax = (float*)(idx + BB * NN * 3);         // B*32*HD
    float4* pts = (float4*)(pmax + BB * NCHUNKS * HD); // B*N float4

    // zero the contiguous [dv | Z1 | Z2] region
    hipMemsetAsync(dv, 0, (size_t)(BB * NN) * (1 + 2 * HD) * sizeof(float), stream);

    k_prep<<<BB * NN / 256, 256, 0, stream>>>(x, pts);
    k_dist<<<dim3(NN / WPB, BB), 256, 0, stream>>>(pts, idx, vals, de, dv);
    k_conv1<<<dim3(NN / 2, BB), 256, 0, stream>>>(W1, idx, vals, de, dv, Z1);
    k_conv2<<<dim3(NN / 2, BB), 256, 0, stream>>>(b1, idx, vals, de, dv, Z1, Z2);
    k_pool1<<<dim3(BB, NCHUNKS), HD, 0, stream>>>(dv, Z2, pmax);
    k_pool2<<<BB, HD, 0, stream>>>(Wc, bc, pmax, out);
}

// Round 7
// 119.268 us; speedup vs baseline: 1.8081x; 1.8081x over previous
//
#include <hip/hip_runtime.h>
#include <math.h>

#define NN 2048
#define BB 4
#define HD 128
#define CNUM 8
#define WPB 4               // waves (= centers) per block in k_dist
#define PCHUNK 64           // nodes per block in k_pool1
#define NCHUNKS (NN / PCHUNK)

typedef unsigned long long u64;

// Branchless top-3: packed key (float-bits(sq) << 32) | j. sq >= 0 so IEEE
// bits are monotonic; u64 order == (sq, j) lexicographic == reference
// tie-break (lowest j wins). 5 min/max (cmp+2cndmask each) per candidate,
// no divergence -- replaces the nested-if insert that made R1-R6 issue-bound.
__device__ __forceinline__ u64 pack_key(float sq, int j) {
    return ((u64)__float_as_uint(sq) << 32) | (unsigned)j;
}
__device__ __forceinline__ void ins3(u64 k, u64& k0, u64& k1, u64& k2) {
    u64 a = k  < k2 ? k  : k2;   // survivor of {k, k2}
    u64 b = k0 > a  ? k0 : a;    // merge a into sorted (k0, k1)
    k0    = k0 < a  ? k0 : a;
    k2    = k1 > b  ? k1 : b;
    k1    = k1 < b  ? k1 : b;
}

// K0: pack (x,y,z,|p|^2) once to global (L2-resident, 128 KB total).
__global__ void k_prep(const float* __restrict__ x, float4* __restrict__ pts) {
    const int t = blockIdx.x * 256 + threadIdx.x;   // [0, B*NN)
    const float a = x[3 * t], c = x[3 * t + 1], d = x[3 * t + 2];
    pts[t] = make_float4(a, c, d, a * a + c * c + d * d);
}

// K1: one wave per center, coalesced global loads, branchless top-3,
// raw v_sqrt_f32, butterfly merge, fused exp/de/dv epilogue.
__global__ __launch_bounds__(256) void k_dist(
        const float4* __restrict__ pts,
        int* __restrict__ idx, float* __restrict__ vals,
        float* __restrict__ de, float* __restrict__ dv) {
    const int b = blockIdx.y;
    const float4* pb = pts + b * NN;
    const int wave = threadIdx.x >> 6;
    const int lane = threadIdx.x & 63;
    const int i = blockIdx.x * WPB + wave;          // this wave's center
    const float4 ci = pb[i];                        // wave-uniform -> broadcast
    u64 k0 = ~0ull, k1 = ~0ull, k2 = ~0ull;
    float dsA = 0.f, dsB = 0.f;
    for (int t = lane; t < NN; t += 256) {          // 8 iterations, 4 elems each
        const float4 pa = pb[t];
        const float4 pv = pb[t + 64];
        const float4 pc = pb[t + 128];
        const float4 pd = pb[t + 192];
        const float qa = fmaxf(ci.w + pa.w - 2.0f * (ci.x * pa.x + ci.y * pa.y + ci.z * pa.z), 0.0f);
        const float qb = fmaxf(ci.w + pv.w - 2.0f * (ci.x * pv.x + ci.y * pv.y + ci.z * pv.z), 0.0f);
        const float qc = fmaxf(ci.w + pc.w - 2.0f * (ci.x * pc.x + ci.y * pc.y + ci.z * pc.z), 0.0f);
        const float qd = fmaxf(ci.w + pd.w - 2.0f * (ci.x * pd.x + ci.y * pd.y + ci.z * pd.z), 0.0f);
        dsA += __builtin_amdgcn_sqrtf(qa + 1e-12f) + __builtin_amdgcn_sqrtf(qc + 1e-12f);
        dsB += __builtin_amdgcn_sqrtf(qb + 1e-12f) + __builtin_amdgcn_sqrtf(qd + 1e-12f);
        ins3(pack_key(qa, t),       k0, k1, k2);
        ins3(pack_key(qb, t + 64),  k0, k1, k2);
        ins3(pack_key(qc, t + 128), k0, k1, k2);
        ins3(pack_key(qd, t + 192), k0, k1, k2);
    }
    float dsum = dsA + dsB;
    // butterfly merge: packed keys are globally unique -> plain u64 merge
    for (int off = 32; off > 0; off >>= 1) {
        const u64 o0 = __shfl_xor(k0, off);
        const u64 o1 = __shfl_xor(k1, off);
        const u64 o2 = __shfl_xor(k2, off);
        dsum += __shfl_xor(dsum, off);
        ins3(o0, k0, k1, k2);
        ins3(o1, k0, k1, k2);
        ins3(o2, k0, k1, k2);
    }
    if (lane == 0) {
        const float s0 = __uint_as_float((unsigned)(k0 >> 32));
        const float s1 = __uint_as_float((unsigned)(k1 >> 32));
        const float s2 = __uint_as_float((unsigned)(k2 >> 32));
        const int   i0 = (int)(k0 & 0xffffffffu);
        const int   i1 = (int)(k1 & 0xffffffffu);
        const int   i2 = (int)(k2 & 0xffffffffu);
        const float avg = dsum * (1.0f / NN);
        const float inva2 = 1.0f / (avg * avg);
        const float v0 = expf(-s0 * inva2);
        const float v1 = expf(-s1 * inva2);
        const float v2 = expf(-s2 * inva2);
        const int base = (b * NN + i) * 3;
        idx[base] = i0; idx[base + 1] = i1; idx[base + 2] = i2;
        vals[base] = v0; vals[base + 1] = v1; vals[base + 2] = v2;
        de[b * NN + i] = v0 + v1 + v2;
        atomicAdd(&dv[b * NN + i0], v0);
        atomicAdd(&dv[b * NN + i1], v1);
        atomicAdd(&dv[b * NN + i2], v2);
    }
}

// K2: first G-application on W1. 256-thread blocks, 2 edges per block.
__global__ void k_conv1(const float* __restrict__ W1, const int* __restrict__ idx,
                        const float* __restrict__ vals, const float* __restrict__ de,
                        const float* __restrict__ dv, float* __restrict__ Z1) {
    const int e = blockIdx.x * 2 + (threadIdx.x >> 7);
    const int b = blockIdx.y, h = threadIdx.x & (HD - 1);
    const int base = (b * NN + e) * 3;
    const int j0 = idx[base], j1 = idx[base + 1], j2 = idx[base + 2];
    const float v0 = vals[base], v1 = vals[base + 1], v2 = vals[base + 2];
    const float ide = 1.0f / de[b * NN + e];
    const float g0 = v0 * rsqrtf(dv[b * NN + j0]);
    const float g1 = v1 * rsqrtf(dv[b * NN + j1]);
    const float g2 = v2 * rsqrtf(dv[b * NN + j2]);
    const float y = ide * (g0 * W1[j0 * HD + h] + g1 * W1[j1 * HD + h] + g2 * W1[j2 * HD + h]);
    atomicAdd(&Z1[((size_t)(b * NN + j0)) * HD + h], v0 * y);
    atomicAdd(&Z1[((size_t)(b * NN + j1)) * HD + h], v1 * y);
    atomicAdd(&Z1[((size_t)(b * NN + j2)) * HD + h], v2 * y);
}

// K3: second G-application on f1 = dv2*Z1 + b1.
__global__ void k_conv2(const float* __restrict__ b1, const int* __restrict__ idx,
                        const float* __restrict__ vals, const float* __restrict__ de,
                        const float* __restrict__ dv, const float* __restrict__ Z1,
                        float* __restrict__ Z2) {
    const int e = blockIdx.x * 2 + (threadIdx.x >> 7);
    const int b = blockIdx.y, h = threadIdx.x & (HD - 1);
    const int base = (b * NN + e) * 3;
    const int j0 = idx[base], j1 = idx[base + 1], j2 = idx[base + 2];
    const float v0 = vals[base], v1 = vals[base + 1], v2 = vals[base + 2];
    const float ide = 1.0f / de[b * NN + e];
    const float bh = b1[h];
    const float d0 = rsqrtf(dv[b * NN + j0]);
    const float d1 = rsqrtf(dv[b * NN + j1]);
    const float d2 = rsqrtf(dv[b * NN + j2]);
    const float f0 = d0 * Z1[((size_t)(b * NN + j0)) * HD + h] + bh;
    const float f1 = d1 * Z1[((size_t)(b * NN + j1)) * HD + h] + bh;
    const float f2 = d2 * Z1[((size_t)(b * NN + j2)) * HD + h] + bh;
    const float y = ide * (v0 * d0 * f0 + v1 * d1 * f1 + v2 * d2 * f2);
    atomicAdd(&Z2[((size_t)(b * NN + j0)) * HD + h], v0 * y);
    atomicAdd(&Z2[((size_t)(b * NN + j1)) * HD + h], v1 * y);
    atomicAdd(&Z2[((size_t)(b * NN + j2)) * HD + h], v2 * y);
}

// K4a: partial max over 64-node chunks. grid (B, 32) x 128 threads.
__global__ void k_pool1(const float* __restrict__ dv, const float* __restrict__ Z2,
                        float* __restrict__ pmax) {
    const int b = blockIdx.x, ch = blockIdx.y, h = threadIdx.x;
    const int v0 = ch * PCHUNK;
    float mx = -INFINITY;
    for (int v = v0; v < v0 + PCHUNK; ++v) {
        const float d2 = rsqrtf(dv[b * NN + v]);
        mx = fmaxf(mx, d2 * Z2[((size_t)(b * NN + v)) * HD + h]);
    }
    pmax[(b * NCHUNKS + ch) * HD + h] = mx;
}

// K4b: merge partial maxes + classifier. grid B x 128 threads.
__global__ void k_pool2(const float* __restrict__ Wc, const float* __restrict__ bc,
                        const float* __restrict__ pmax, float* __restrict__ out) {
    __shared__ float smax[HD];
    const int b = blockIdx.x, h = threadIdx.x;
    float mx = -INFINITY;
    for (int c = 0; c < NCHUNKS; ++c)
        mx = fmaxf(mx, pmax[(b * NCHUNKS + c) * HD + h]);
    smax[h] = mx;
    __syncthreads();
    if (h < CNUM) {
        float acc = bc[h];
        for (int q = 0; q < HD; ++q) acc += smax[q] * Wc[q * CNUM + h];
        out[b * CNUM + h] = acc;
    }
}

extern "C" void kernel_launch(void* const* d_in, const int* in_sizes, int n_in,
                              void* d_out, int out_size, void* d_ws, size_t ws_size,
                              hipStream_t stream) {
    const float* x  = (const float*)d_in[0];   // [B,N,3]
    const float* W1 = (const float*)d_in[1];   // [N,H1]
    const float* b1 = (const float*)d_in[2];   // [H1]
    const float* Wc = (const float*)d_in[3];   // [H1,C]
    const float* bc = (const float*)d_in[4];   // [C]
    float* out = (float*)d_out;                // [B,C]

    float* ws = (float*)d_ws;
    float* dv   = ws;                                  // B*N           (zeroed)
    float* Z1   = dv + BB * NN;                        // B*N*HD        (zeroed)
    float* Z2   = Z1 + (size_t)BB * NN * HD;           // B*N*HD        (zeroed)
    float* vals = Z2 + (size_t)BB * NN * HD;           // B*N*3
    float* de   = vals + BB * NN * 3;                  // B*N
    int*   idx  = (int*)(de + BB * NN);                // B*N*3
    float* pmax = (float*)(idx + BB * NN * 3);         // B*32*HD
    float4* pts = (float4*)(pmax + BB * NCHUNKS * HD); // B*N float4

    // zero the contiguous [dv | Z1 | Z2] region
    hipMemsetAsync(dv, 0, (size_t)(BB * NN) * (1 + 2 * HD) * sizeof(float), stream);

    k_prep<<<BB * NN / 256, 256, 0, stream>>>(x, pts);
    k_dist<<<dim3(NN / WPB, BB), 256, 0, stream>>>(pts, idx, vals, de, dv);
    k_conv1<<<dim3(NN / 2, BB), 256, 0, stream>>>(W1, idx, vals, de, dv, Z1);
    k_conv2<<<dim3(NN / 2, BB), 256, 0, stream>>>(b1, idx, vals, de, dv, Z1, Z2);
    k_pool1<<<dim3(BB, NCHUNKS), HD, 0, stream>>>(dv, Z2, pmax);
    k_pool2<<<BB, HD, 0, stream>>>(Wc, bc, pmax, out);
}